// Round 8
// baseline (197.349 us; speedup 1.0000x reference)
//
#include <hip/hip_runtime.h>
#include <math.h>

typedef unsigned int u32;
typedef unsigned long long u64;

#define NN 50000
#define NE 800000
#define TOPK 8
#define RSTRIDE 64            // fixed CSR slots/row; P(deg>64) ~ 1e-15 for Poisson(16)
#define GTILES 782            // ceil(NN/64) gemm tiles == ceil(NE/1024) edge chunks

__device__ __forceinline__ u64 shflxor64(u64 v, int m) {
    int lo = __shfl_xor((int)(u32)v, m);
    int hi = __shfl_xor((int)(u32)(v >> 32), m);
    return ((u64)(u32)hi << 32) | (u32)lo;
}

// ---------------- fused gemm + degscat IN THE SAME BLOCK ----------------
// vmcnt discipline (the round-7 lesson): vmcnt retires IN ORDER, so any
// vm-op issued after the atomics forces later waits to drain the atomics
// too. Therefore: edge loads issued FIRST (retire early); atomics issued
// ONLY after the LAST staging loads (post kk=64 barrier) — after that the
// only vmcnt consumer is the ccsr store at the kernel tail. Epilogue does
// all rk-independent stores (h, s_i, s_j) BEFORE the ccsr scatter.
// deg[] zeroed by prior memset.
__global__ __launch_bounds__(256) void gemmdeg_k(const float* __restrict__ x,
                                                 const float* __restrict__ W,
                                                 const float* __restrict__ att,
                                                 const int* __restrict__ ei,
                                                 float* __restrict__ hbuf,
                                                 float* __restrict__ s_i,
                                                 float* __restrict__ s_j,
                                                 int* __restrict__ deg,
                                                 u32* __restrict__ ccsr) {
    __shared__ float xst[64][68];     // [k][r] transposed, 17.4 KB
    __shared__ float ws[64][128];     // [k][c], 32 KB  -> 49.4 KB, 3 blocks/CU
    const int t = threadIdx.x;
    const int cx = t & 15;            // col group: cols cx*8..+7
    const int ry = t >> 4;            // row group: rows ry*4..+3
    const int rbase = blockIdx.x * 64;

    // edge chunk loads issued first — coalesced, retire long before use
    const int e4 = blockIdx.x * 1024 + t * 4;
    const bool ev = e4 < NE;
    int4 er = make_int4(0, 0, 0, 0), ec = make_int4(0, 0, 0, 0);
    if (ev) {
        er = *reinterpret_cast<const int4*>(ei + e4);
        ec = *reinterpret_cast<const int4*>(ei + NE + e4);
    }
    int rk0 = RSTRIDE, rk1 = RSTRIDE, rk2 = RSTRIDE, rk3 = RSTRIDE;

    float acc[4][8];
    #pragma unroll
    for (int i = 0; i < 4; ++i)
        #pragma unroll
        for (int j = 0; j < 8; ++j) acc[i][j] = 0.f;

    for (int kk = 0; kk < 128; kk += 64) {
        if (kk) __syncthreads();
        #pragma unroll
        for (int rr = ry; rr < 64; rr += 16) {
            int gr = rbase + rr;
            float4 v = make_float4(0.f, 0.f, 0.f, 0.f);
            if (gr < NN)
                v = *reinterpret_cast<const float4*>(x + (size_t)gr * 128 + kk + cx * 4);
            xst[cx * 4 + 0][rr] = v.x;
            xst[cx * 4 + 1][rr] = v.y;
            xst[cx * 4 + 2][rr] = v.z;
            xst[cx * 4 + 3][rr] = v.w;
        }
        #pragma unroll
        for (int wk = t >> 5; wk < 64; wk += 8) {
            float4 v = *reinterpret_cast<const float4*>(W + (size_t)(kk + wk) * 128 + (t & 31) * 4);
            *reinterpret_cast<float4*>(&ws[wk][(t & 31) * 4]) = v;
        }
        __syncthreads();

        if (kk && ev) {
            // LAST staging done -> no future vmcnt consumer until rk use at
            // the kernel tail. Atomic latency hides under the 64-k loop.
            rk0 = atomicAdd(deg + er.x, 1);
            rk1 = atomicAdd(deg + er.y, 1);
            rk2 = atomicAdd(deg + er.z, 1);
            rk3 = atomicAdd(deg + er.w, 1);
        }

        for (int k = 0; k < 64; ++k) {
            float4 xa = *reinterpret_cast<const float4*>(&xst[k][ry * 4]);
            float4 wa = *reinterpret_cast<const float4*>(&ws[k][cx * 8]);
            float4 wb = *reinterpret_cast<const float4*>(&ws[k][cx * 8 + 4]);
            float xv[4] = {xa.x, xa.y, xa.z, xa.w};
            float wv[8] = {wa.x, wa.y, wa.z, wa.w, wb.x, wb.y, wb.z, wb.w};
            #pragma unroll
            for (int i = 0; i < 4; ++i)
                #pragma unroll
                for (int j = 0; j < 8; ++j) acc[i][j] += xv[i] * wv[j];
        }
    }

    // epilogue: ALL rk-independent stores first (h + s_i/s_j) ...
    const int head = cx >> 2;
    float aiv[8], ajv[8];
    #pragma unroll
    for (int j = 0; j < 8; ++j) {
        aiv[j] = att[head * 64 + (cx & 3) * 8 + j];
        ajv[j] = att[head * 64 + 32 + (cx & 3) * 8 + j];
    }
    #pragma unroll
    for (int i = 0; i < 4; ++i) {
        int gr = rbase + ry * 4 + i;
        float pi = 0.f, pj = 0.f;
        #pragma unroll
        for (int j = 0; j < 8; ++j) {
            pi += acc[i][j] * aiv[j];
            pj += acc[i][j] * ajv[j];
        }
        pi += __shfl_xor(pi, 1); pi += __shfl_xor(pi, 2);
        pj += __shfl_xor(pj, 1); pj += __shfl_xor(pj, 2);
        if (gr < NN) {
            float* dst = hbuf + (size_t)gr * 128 + cx * 8;
            *reinterpret_cast<float4*>(dst)     = make_float4(acc[i][0], acc[i][1], acc[i][2], acc[i][3]);
            *reinterpret_cast<float4*>(dst + 4) = make_float4(acc[i][4], acc[i][5], acc[i][6], acc[i][7]);
            if ((cx & 3) == 0) {
                s_i[(size_t)gr * 4 + head] = pi;
                s_j[(size_t)gr * 4 + head] = pj;
            }
        }
    }

    // ... then the rank-dependent ccsr scatter (only stall is here, at tail)
    if (ev) {
        if (rk0 < RSTRIDE) ccsr[(size_t)er.x * RSTRIDE + rk0] = (u32)ec.x;
        if (rk1 < RSTRIDE) ccsr[(size_t)er.y * RSTRIDE + rk1] = (u32)ec.y;
        if (rk2 < RSTRIDE) ccsr[(size_t)er.z * RSTRIDE + rk2] = (u32)ec.z;
        if (rk3 < RSTRIDE) ccsr[(size_t)er.w * RSTRIDE + rk3] = (u32)ec.w;
    }
}

// ---------------- fused: split-half top-k + merge + softmax + aggregate ----------------
// 32 rows/block; 8 threads/row = 4 heads x 2 halves. Self-loop candidate
// synthesized in half 0 (never in CSR). Key = sortable-float(s_j)<<32 | ~slot;
// slot-index tie-break is exact for this input: distinct-col exact ties are
// measure-zero, same-col duplicate edges are output-invariant, self-loop's
// ~(NE+row) < ~slot keeps it last among equals (lexsort stability).
// Phase 1: simple per-candidate loop (compiler pipelines; batching was slower).
// Phase 2: lane=(pair,d) float4 gathers, 8 independent 16B loads in flight.
__global__ __launch_bounds__(256) void rowsel_k(const int* __restrict__ deg,
                                                const u32* __restrict__ ccsr,
                                                const float* __restrict__ s_i,
                                                const float* __restrict__ s_j,
                                                const float* __restrict__ hbuf,
                                                float* __restrict__ out) {
    __shared__ float lal[32 * 4 * 8];   // normalized alpha, [pair p][k] = [p*8+k]
    __shared__ int   lcl[32 * 4 * 8];   // col
    const int t = threadIdx.x;
    const int rbase = blockIdx.x * 32;
    const int lr = t >> 3;
    const int head = (t >> 1) & 3;
    const int half = t & 1;
    const int row = rbase + lr;

    u64 kl[TOPK];
    int cl[TOPK];
    #pragma unroll
    for (int i = 0; i < TOPK; ++i) { kl[i] = 0ull; cl[i] = 0; }

    int dg = 0;
    size_t o0 = (size_t)row * RSTRIDE;
    if (row < NN) {
        dg = deg[row];
        dg = (dg > RSTRIDE) ? RSTRIDE : dg;
    }

    if (half == 0 && row < NN) {
        // synthetic self-loop candidate (loses ties to any real edge)
        float v = s_j[(size_t)row * 4 + head];
        u32 b = __float_as_uint(v);
        u32 fk = (b & 0x80000000u) ? ~b : (b | 0x80000000u);
        u64 key = ((u64)fk << 32) | (u32)(~(u32)(NE + row));
        kl[0] = key; cl[0] = row;
    }

    for (int j = half; j < dg; j += 2) {
        u32 col = ccsr[o0 + j];
        float v = s_j[(size_t)col * 4 + head];
        u32 b = __float_as_uint(v);
        u32 fk = (b & 0x80000000u) ? ~b : (b | 0x80000000u);
        u64 key = ((u64)fk << 32) | (u32)(~(u32)j);
        int cc = (int)col;
        #pragma unroll
        for (int i = 0; i < TOPK; ++i) {
            bool gt = key > kl[i];
            u64 tk = gt ? kl[i] : key;  kl[i] = gt ? key : kl[i];  key = tk;
            int tc = gt ? cl[i] : cc;   cl[i] = gt ? cc : cl[i];   cc = tc;
        }
    }

    // merge with partner (t^1): top-8 of union = max(A[i], B[7-i])
    u64 mk[TOPK]; int mc[TOPK];
    #pragma unroll
    for (int i = 0; i < TOPK; ++i) {
        u64 pk = shflxor64(kl[TOPK - 1 - i], 1);
        int pc = __shfl_xor(cl[TOPK - 1 - i], 1);
        bool mine = kl[i] >= pk;
        mk[i] = mine ? kl[i] : pk;
        mc[i] = mine ? cl[i] : pc;
    }
    u64 pk0 = shflxor64(kl[0], 1);
    u64 mxk = (kl[0] >= pk0) ? kl[0] : pk0;

    float si = (row < NN) ? s_i[(size_t)row * 4 + head] : 0.f;
    {
        u32 fk = (u32)(mxk >> 32);
        u32 b = (fk & 0x80000000u) ? (fk ^ 0x80000000u) : ~fk;
        float vmax = __uint_as_float(b);
        float em = si + vmax;
        float m = (em >= 0.f) ? em : 0.2f * em;
        float al[TOPK];
        float denom = 0.f;
        #pragma unroll
        for (int i = 0; i < TOPK; ++i) {
            u32 fki = (u32)(mk[i] >> 32);
            u32 bi = (fki & 0x80000000u) ? (fki ^ 0x80000000u) : ~fki;
            float v = __uint_as_float(bi);
            float e = si + v;
            e = (e >= 0.f) ? e : 0.2f * e;
            float z = (mk[i] != 0ull) ? __expf(e - m) : 0.f;
            al[i] = z;
            denom += z;
        }
        float inv = 1.f / denom;
        if (row < NN && half == 0) {
            const int base = (lr * 4 + head) * 8;
            #pragma unroll
            for (int i = 0; i < TOPK; ++i) {
                lal[base + i] = al[i] * inv;
                lcl[base + i] = mc[i];
            }
        }
    }
    __syncthreads();

    // phase 2: 128 (row,head) pairs per block; lane=(pair q, float4 slot dq).
    const int lane = t & 63;
    const int wid = t >> 6;
    const int q = lane >> 3;
    const int dq = lane & 7;
    for (int g = wid; g < 16; g += 4) {
        const int p = g * 8 + q;          // pair 0..127 == (lr2*4+hh)
        const int r = rbase + (p >> 2);
        const int hh = p & 3;
        if (r < NN) {
            const int base = p * 8;
            float av[8]; int cv[8];
            #pragma unroll
            for (int k = 0; k < 8; ++k) { av[k] = lal[base + k]; cv[k] = lcl[base + k]; }
            float4 a4 = make_float4(0.f, 0.f, 0.f, 0.f);
            #pragma unroll
            for (int k = 0; k < 8; ++k) {
                const float4 hv = *reinterpret_cast<const float4*>(
                    &hbuf[(size_t)cv[k] * 128 + hh * 32 + dq * 4]);
                a4.x += av[k] * hv.x;
                a4.y += av[k] * hv.y;
                a4.z += av[k] * hv.z;
                a4.w += av[k] * hv.w;
            }
            a4.x = (a4.x > 0.f) ? a4.x : expm1f(a4.x);
            a4.y = (a4.y > 0.f) ? a4.y : expm1f(a4.y);
            a4.z = (a4.z > 0.f) ? a4.z : expm1f(a4.z);
            a4.w = (a4.w > 0.f) ? a4.w : expm1f(a4.w);
            *reinterpret_cast<float4*>(&out[(size_t)r * 128 + hh * 32 + dq * 4]) = a4;
        }
    }
}

extern "C" void kernel_launch(void* const* d_in, const int* in_sizes, int n_in,
                              void* d_out, int out_size, void* d_ws, size_t ws_size,
                              hipStream_t stream) {
    const float* x   = (const float*)d_in[0];   // 50000x128 f32
    const float* W   = (const float*)d_in[1];   // 128x128  f32
    const float* att = (const float*)d_in[2];   // 4x64     f32
    const int*   ei  = (const int*)d_in[3];     // 2x800000 int32
    float* out = (float*)d_out;                 // 50000x128 f32

    u32* ccsr    = (u32*)d_ws;                  // 50000*64 u32 = 12.8 MB
    float* hbuf  = (float*)(ccsr + (size_t)NN * RSTRIDE);  // 6.4M f32
    float* s_i   = hbuf + 6400000;              // 200k f32
    float* s_j   = s_i + 200000;                // 200k f32
    int* deg     = (int*)(s_j + 200000);        // 50k
    // total ws: ~40 MB

    hipMemsetAsync(deg, 0, NN * sizeof(int), stream);
    gemmdeg_k<<<GTILES, 256, 0, stream>>>(x, W, att, ei, hbuf, s_i, s_j, deg, ccsr);
    rowsel_k<<<(NN + 31) / 32, 256, 0, stream>>>(deg, ccsr, s_i, s_j, hbuf, out);
}

// Round 9
// 173.570 us; speedup vs baseline: 1.1370x; 1.1370x over previous
//
#include <hip/hip_runtime.h>
#include <math.h>

typedef unsigned int u32;
typedef unsigned long long u64;

#define NN 50000
#define NE 800000
#define TOPK 8
#define NB 196           // coarse buckets of 256 rows (196*256 = 50176 >= NN)
#define BCAP 4608        // bucket capacity: mean 4082 + ~8 sigma
#define CURSTRIDE 16     // cursor padding: one counter per 64B line
#define GTILES 782       // ceil(NN/64) gemm tiles
#define PBLOCKS 391      // ceil(NE/2048) partition blocks

// ---------------- gemm: h = x @ W + fused s_i/s_j ----------------
// BM=64, 4x8 register tile, 49.4 KB LDS -> 3 blocks/CU, grid 782.
// Block 0 also zeroes the 196 padded bucket cursors (12.5 KB) for part_k.
__global__ __launch_bounds__(256) void gemm_k(const float* __restrict__ x,
                                              const float* __restrict__ W,
                                              const float* __restrict__ att,
                                              float* __restrict__ hbuf,
                                              float* __restrict__ s_i,
                                              float* __restrict__ s_j,
                                              int* __restrict__ cursor) {
    __shared__ float xst[64][68];     // [k][r] transposed, 17.4 KB
    __shared__ float ws[64][128];     // [k][c], 32 KB
    const int t = threadIdx.x;
    const int cx = t & 15;            // col group: cols cx*8..+7
    const int ry = t >> 4;            // row group: rows ry*4..+3
    const int rbase = blockIdx.x * 64;

    if (blockIdx.x == 0 && t < NB) cursor[t * CURSTRIDE] = 0;

    float acc[4][8];
    #pragma unroll
    for (int i = 0; i < 4; ++i)
        #pragma unroll
        for (int j = 0; j < 8; ++j) acc[i][j] = 0.f;

    for (int kk = 0; kk < 128; kk += 64) {
        if (kk) __syncthreads();
        #pragma unroll
        for (int rr = ry; rr < 64; rr += 16) {
            int gr = rbase + rr;
            float4 v = make_float4(0.f, 0.f, 0.f, 0.f);
            if (gr < NN)
                v = *reinterpret_cast<const float4*>(x + (size_t)gr * 128 + kk + cx * 4);
            xst[cx * 4 + 0][rr] = v.x;
            xst[cx * 4 + 1][rr] = v.y;
            xst[cx * 4 + 2][rr] = v.z;
            xst[cx * 4 + 3][rr] = v.w;
        }
        #pragma unroll
        for (int wk = t >> 5; wk < 64; wk += 8) {
            float4 v = *reinterpret_cast<const float4*>(W + (size_t)(kk + wk) * 128 + (t & 31) * 4);
            *reinterpret_cast<float4*>(&ws[wk][(t & 31) * 4]) = v;
        }
        __syncthreads();

        for (int k = 0; k < 64; ++k) {
            float4 xa = *reinterpret_cast<const float4*>(&xst[k][ry * 4]);
            float4 wa = *reinterpret_cast<const float4*>(&ws[k][cx * 8]);
            float4 wb = *reinterpret_cast<const float4*>(&ws[k][cx * 8 + 4]);
            float xv[4] = {xa.x, xa.y, xa.z, xa.w};
            float wv[8] = {wa.x, wa.y, wa.z, wa.w, wb.x, wb.y, wb.z, wb.w};
            #pragma unroll
            for (int i = 0; i < 4; ++i)
                #pragma unroll
                for (int j = 0; j < 8; ++j) acc[i][j] += xv[i] * wv[j];
        }
    }

    const int head = cx >> 2;
    float aiv[8], ajv[8];
    #pragma unroll
    for (int j = 0; j < 8; ++j) {
        aiv[j] = att[head * 64 + (cx & 3) * 8 + j];
        ajv[j] = att[head * 64 + 32 + (cx & 3) * 8 + j];
    }
    #pragma unroll
    for (int i = 0; i < 4; ++i) {
        int gr = rbase + ry * 4 + i;
        float pi = 0.f, pj = 0.f;
        #pragma unroll
        for (int j = 0; j < 8; ++j) {
            pi += acc[i][j] * aiv[j];
            pj += acc[i][j] * ajv[j];
        }
        pi += __shfl_xor(pi, 1); pi += __shfl_xor(pi, 2);
        pj += __shfl_xor(pj, 1); pj += __shfl_xor(pj, 2);
        if (gr < NN) {
            float* dst = hbuf + (size_t)gr * 128 + cx * 8;
            *reinterpret_cast<float4*>(dst)     = make_float4(acc[i][0], acc[i][1], acc[i][2], acc[i][3]);
            *reinterpret_cast<float4*>(dst + 4) = make_float4(acc[i][4], acc[i][5], acc[i][6], acc[i][7]);
            if ((cx & 3) == 0) {
                s_i[(size_t)gr * 4 + head] = pi;
                s_j[(size_t)gr * 4 + head] = pj;
            }
        }
    }
}

// ---------------- partition: edges -> 196 coarse buckets (LDS-combined) ----------------
// 2048 edges/block. LDS histogram over 196 buckets (LDS atomics, returns
// local rank), ONE padded global atomicAdd per (block,bucket) -> ~77k global
// atomics total (vs 800k before: the ~60us atomic wall). Entry packs
// (row&255)<<16 | col (col < 2^16 since NN=50000).
__global__ __launch_bounds__(256) void part_k(const int* __restrict__ ei,
                                              int* __restrict__ cursor,
                                              u32* __restrict__ breg) {
    __shared__ u32 cnt[NB];
    __shared__ u32 base[NB];
    const int t = threadIdx.x;
    if (t < NB) cnt[t] = 0;
    __syncthreads();

    const int e0 = blockIdx.x * 2048 + t * 8;   // NE%8==0 -> all-or-nothing
    const bool ev = e0 < NE;
    int rows[8], cols[8], bk[8];
    u32 lrk[8];
    if (ev) {
        int4 ra = *reinterpret_cast<const int4*>(ei + e0);
        int4 rb = *reinterpret_cast<const int4*>(ei + e0 + 4);
        int4 ca = *reinterpret_cast<const int4*>(ei + NE + e0);
        int4 cb = *reinterpret_cast<const int4*>(ei + NE + e0 + 4);
        rows[0] = ra.x; rows[1] = ra.y; rows[2] = ra.z; rows[3] = ra.w;
        rows[4] = rb.x; rows[5] = rb.y; rows[6] = rb.z; rows[7] = rb.w;
        cols[0] = ca.x; cols[1] = ca.y; cols[2] = ca.z; cols[3] = ca.w;
        cols[4] = cb.x; cols[5] = cb.y; cols[6] = cb.z; cols[7] = cb.w;
        #pragma unroll
        for (int i = 0; i < 8; ++i) {
            bk[i] = rows[i] >> 8;
            lrk[i] = atomicAdd(&cnt[bk[i]], 1u);
        }
    }
    __syncthreads();
    if (t < NB) base[t] = (cnt[t] > 0) ? (u32)atomicAdd(cursor + t * CURSTRIDE, (int)cnt[t]) : 0u;
    __syncthreads();
    if (ev) {
        #pragma unroll
        for (int i = 0; i < 8; ++i) {
            u32 pos = base[bk[i]] + lrk[i];
            if (pos < BCAP)
                breg[(size_t)bk[i] * BCAP + pos] = ((u32)(rows[i] & 255) << 16) | (u32)cols[i];
        }
    }
}

// ---------------- rowsel: LDS CSR build + top-k + softmax + aggregate ----------------
// 4 sub-blocks per bucket, 64 rows each. Block re-reads its bucket's packed
// edges (~16KB, L2-hot), LDS-atomics build lcsr[64][65] (padded: conflict-free
// column reads). Top-k: 1 thread per (row,head), candidates read from LDS,
// s_j scored from global (L2-resident); softmax fully thread-local (no merge
// shuffles). Key = sortable-float(s_j)<<32 | ~slot; slot tie-break exact:
// distinct-col float ties measure-zero, same-col ties output-invariant,
// self-loop's ~(NE+row) < ~slot keeps it last among equals.
// Phase 2: lane=(pair,dq) float4 gathers, 8 independent 16B loads in flight.
__global__ __launch_bounds__(256) void rowsel_k(const int* __restrict__ cursor,
                                                const u32* __restrict__ breg,
                                                const float* __restrict__ s_i,
                                                const float* __restrict__ s_j,
                                                const float* __restrict__ hbuf,
                                                float* __restrict__ out) {
    __shared__ u32 lcsr[64][65];        // 16.6 KB, +1 pad breaks bank aliasing
    __shared__ u32 ldeg[64];
    __shared__ float lal[256 * 8];      // 8 KB
    __shared__ int   lcl[256 * 8];      // 8 KB
    const int t = threadIdx.x;
    const int B = blockIdx.x >> 2;
    const int s = blockIdx.x & 3;
    const int rbase = B * 256 + s * 64;

    if (t < 64) ldeg[t] = 0;
    __syncthreads();

    int n = cursor[B * CURSTRIDE];
    if (n > BCAP) n = BCAP;
    const u32* reg = breg + (size_t)B * BCAP;
    for (int i = t; i < n; i += 256) {
        u32 e = reg[i];
        if ((int)(e >> 22) == s) {
            int lr = (int)((e >> 16) & 63);
            u32 rk = atomicAdd(&ldeg[lr], 1u);
            if (rk < 64) lcsr[lr][rk] = e & 0xFFFFu;
        }
    }
    __syncthreads();

    // top-k: thread t = lrow*4 + head
    const int lrow = t >> 2;
    const int head = t & 3;
    const int row = rbase + lrow;

    u64 kl[TOPK];
    int cl[TOPK];
    #pragma unroll
    for (int i = 0; i < TOPK; ++i) { kl[i] = 0ull; cl[i] = 0; }

    int dgr = 0;
    if (row < NN) {
        dgr = (int)ldeg[lrow];
        if (dgr > 64) dgr = 64;
        // synthetic self-loop candidate (loses ties to any real slot)
        float v = s_j[(size_t)row * 4 + head];
        u32 b = __float_as_uint(v);
        u32 fk = (b & 0x80000000u) ? ~b : (b | 0x80000000u);
        kl[0] = ((u64)fk << 32) | (u32)(~(u32)(NE + row));
        cl[0] = row;
    }

    for (int j = 0; j < dgr; ++j) {
        int col = (int)lcsr[lrow][j];
        float v = s_j[(size_t)col * 4 + head];
        u32 b = __float_as_uint(v);
        u32 fk = (b & 0x80000000u) ? ~b : (b | 0x80000000u);
        u64 key = ((u64)fk << 32) | (u32)(~(u32)j);
        int cc = col;
        if (key > kl[TOPK - 1]) {
            #pragma unroll
            for (int i = 0; i < TOPK; ++i) {
                bool gt = key > kl[i];
                u64 tk = gt ? kl[i] : key;  kl[i] = gt ? key : kl[i];  key = tk;
                int tc = gt ? cl[i] : cc;   cl[i] = gt ? cc : cl[i];   cc = tc;
            }
        }
    }

    // softmax: fully thread-local (kl[0] is the max)
    {
        float si = (row < NN) ? s_i[(size_t)row * 4 + head] : 0.f;
        u32 fk = (u32)(kl[0] >> 32);
        u32 b = (fk & 0x80000000u) ? (fk ^ 0x80000000u) : ~fk;
        float vmax = __uint_as_float(b);
        float em = si + vmax;
        float m = (em >= 0.f) ? em : 0.2f * em;
        float al[TOPK];
        float denom = 0.f;
        #pragma unroll
        for (int i = 0; i < TOPK; ++i) {
            u32 fki = (u32)(kl[i] >> 32);
            u32 bi = (fki & 0x80000000u) ? (fki ^ 0x80000000u) : ~fki;
            float v = __uint_as_float(bi);
            float e = si + v;
            e = (e >= 0.f) ? e : 0.2f * e;
            float z = (kl[i] != 0ull) ? __expf(e - m) : 0.f;
            al[i] = z;
            denom += z;
        }
        float inv = 1.f / denom;
        #pragma unroll
        for (int i = 0; i < TOPK; ++i) {
            lal[t * 8 + i] = al[i] * inv;
            lcl[t * 8 + i] = cl[i];
        }
    }
    __syncthreads();

    // phase 2: 256 (row,head) pairs; lane=(pair q, float4 slot dq)
    const int lane = t & 63;
    const int wid = t >> 6;
    const int q = lane >> 3;
    const int dq = lane & 7;
    for (int g = wid; g < 32; g += 4) {
        const int p = g * 8 + q;          // pair 0..255 == lrow*4+hh
        const int r = rbase + (p >> 2);
        const int hh = p & 3;
        if (r < NN) {
            const int base = p * 8;
            float av[8]; int cv[8];
            #pragma unroll
            for (int k = 0; k < 8; ++k) { av[k] = lal[base + k]; cv[k] = lcl[base + k]; }
            float4 a4 = make_float4(0.f, 0.f, 0.f, 0.f);
            #pragma unroll
            for (int k = 0; k < 8; ++k) {
                const float4 hv = *reinterpret_cast<const float4*>(
                    &hbuf[(size_t)cv[k] * 128 + hh * 32 + dq * 4]);
                a4.x += av[k] * hv.x;
                a4.y += av[k] * hv.y;
                a4.z += av[k] * hv.z;
                a4.w += av[k] * hv.w;
            }
            a4.x = (a4.x > 0.f) ? a4.x : expm1f(a4.x);
            a4.y = (a4.y > 0.f) ? a4.y : expm1f(a4.y);
            a4.z = (a4.z > 0.f) ? a4.z : expm1f(a4.z);
            a4.w = (a4.w > 0.f) ? a4.w : expm1f(a4.w);
            *reinterpret_cast<float4*>(&out[(size_t)r * 128 + hh * 32 + dq * 4]) = a4;
        }
    }
}

extern "C" void kernel_launch(void* const* d_in, const int* in_sizes, int n_in,
                              void* d_out, int out_size, void* d_ws, size_t ws_size,
                              hipStream_t stream) {
    const float* x   = (const float*)d_in[0];   // 50000x128 f32
    const float* W   = (const float*)d_in[1];   // 128x128  f32
    const float* att = (const float*)d_in[2];   // 4x64     f32
    const int*   ei  = (const int*)d_in[3];     // 2x800000 int32
    float* out = (float*)d_out;                 // 50000x128 f32

    u32* breg    = (u32*)d_ws;                  // 196*4608 u32 = 3.6 MB
    float* hbuf  = (float*)(breg + (size_t)NB * BCAP);  // 6.4M f32 = 25.6 MB
    float* s_i   = hbuf + 6400000;              // 200k f32
    float* s_j   = s_i + 200000;                // 200k f32
    int* cursor  = (int*)(s_j + 200000);        // 196*16 ints (64B-padded)
    // total ws: ~31 MB

    gemm_k<<<GTILES, 256, 0, stream>>>(x, W, att, hbuf, s_i, s_j, cursor);
    part_k<<<PBLOCKS, 256, 0, stream>>>(ei, cursor, breg);
    rowsel_k<<<NB * 4, 256, 0, stream>>>(cursor, breg, s_i, s_j, hbuf, out);
}

// Round 11
// 167.821 us; speedup vs baseline: 1.1759x; 1.0343x over previous
//
#include <hip/hip_runtime.h>
#include <math.h>

typedef unsigned int u32;
typedef unsigned short u16;
typedef unsigned long long u64;

#define NN 50000
#define NE 800000
#define TOPK 8
#define NB 196           // coarse buckets of 256 rows (196*256 = 50176 >= NN)
#define BCAP 4608        // bucket capacity: mean 4082 + ~8 sigma
#define CURSTRIDE 16     // cursor padding: one counter per 64B line
#define GTILES 782       // ceil(NN/64) gemm tiles == edge chunks of 1024

// ---------------- gemm + edge partition fused ----------------
// Block b: gemm tile b (rows b*64..+63) AND edge chunk b (1024 edges).
// Partition: LDS histogram over 196 buckets (LDS atomics), ONE padded global
// atomicAdd per (block,bucket) at the kk=64 staging point (~150k total, ~11us
// of atomic throughput, hidden under compute); atomic returns parked in a
// register and written to LDS only AFTER the epilogue -> no mid-kernel vmcnt
// stall (R8 lesson). Scatter of packed (row&255)<<16|col entries at the tail.
// cursor[] zeroed by prior 12.5KB memset.
__global__ __launch_bounds__(256) void gemm_k(const float* __restrict__ x,
                                              const float* __restrict__ W,
                                              const float* __restrict__ att,
                                              const int* __restrict__ ei,
                                              float* __restrict__ hbuf,
                                              float* __restrict__ s_i,
                                              float* __restrict__ s_j,
                                              int* __restrict__ cursor,
                                              u32* __restrict__ breg) {
    __shared__ float xst[64][68];     // [k][r] transposed, 17.4 KB
    __shared__ float ws[64][128];     // [k][c], 32 KB
    __shared__ u32 cnt[NB];           // 784 B
    __shared__ u32 base[NB];          // 784 B   -> 51.7 KB total, 3 blocks/CU
    const int t = threadIdx.x;
    const int cx = t & 15;            // col group: cols cx*8..+7
    const int ry = t >> 4;            // row group: rows ry*4..+3
    const int rbase = blockIdx.x * 64;

    // edge chunk loads first (oldest vm ops -> retire before first use)
    const int e0 = blockIdx.x * 1024 + t * 4;
    const bool ev = e0 < NE;
    int4 er = make_int4(0, 0, 0, 0), ec = make_int4(0, 0, 0, 0);
    if (ev) {
        er = *reinterpret_cast<const int4*>(ei + e0);
        ec = *reinterpret_cast<const int4*>(ei + NE + e0);
    }
    if (t < NB) cnt[t] = 0;

    int bk[4];
    u32 lrk[4] = {0, 0, 0, 0};
    u32 myBase = 0;

    float acc[4][8];
    #pragma unroll
    for (int i = 0; i < 4; ++i)
        #pragma unroll
        for (int j = 0; j < 8; ++j) acc[i][j] = 0.f;

    for (int kk = 0; kk < 128; kk += 64) {
        if (kk) __syncthreads();
        #pragma unroll
        for (int rr = ry; rr < 64; rr += 16) {
            int gr = rbase + rr;
            float4 v = make_float4(0.f, 0.f, 0.f, 0.f);
            if (gr < NN)
                v = *reinterpret_cast<const float4*>(x + (size_t)gr * 128 + kk + cx * 4);
            xst[cx * 4 + 0][rr] = v.x;
            xst[cx * 4 + 1][rr] = v.y;
            xst[cx * 4 + 2][rr] = v.z;
            xst[cx * 4 + 3][rr] = v.w;
        }
        #pragma unroll
        for (int wk = t >> 5; wk < 64; wk += 8) {
            float4 v = *reinterpret_cast<const float4*>(W + (size_t)(kk + wk) * 128 + (t & 31) * 4);
            *reinterpret_cast<float4*>(&ws[wk][(t & 31) * 4]) = v;
        }
        __syncthreads();   // staging visible; also orders cnt zero / histogram / base

        if (kk == 0) {
            if (ev) {      // LDS histogram (edges retired by the staging drain)
                int rows[4] = {er.x, er.y, er.z, er.w};
                #pragma unroll
                for (int i = 0; i < 4; ++i) {
                    bk[i] = rows[i] >> 8;
                    lrk[i] = atomicAdd(&cnt[bk[i]], 1u);
                }
            }
        } else {
            // all histogram atomics complete (barrier above); issue cursor
            // atomics now — return consumed only after the epilogue.
            if (t < NB && cnt[t] > 0)
                myBase = (u32)atomicAdd(cursor + t * CURSTRIDE, (int)cnt[t]);
        }

        for (int k = 0; k < 64; ++k) {
            float4 xa = *reinterpret_cast<const float4*>(&xst[k][ry * 4]);
            float4 wa = *reinterpret_cast<const float4*>(&ws[k][cx * 8]);
            float4 wb = *reinterpret_cast<const float4*>(&ws[k][cx * 8 + 4]);
            float xv[4] = {xa.x, xa.y, xa.z, xa.w};
            float wv[8] = {wa.x, wa.y, wa.z, wa.w, wb.x, wb.y, wb.z, wb.w};
            #pragma unroll
            for (int i = 0; i < 4; ++i)
                #pragma unroll
                for (int j = 0; j < 8; ++j) acc[i][j] += xv[i] * wv[j];
        }
    }

    // epilogue: h + s_i/s_j (independent of the cursor atomics)
    const int head = cx >> 2;
    float aiv[8], ajv[8];
    #pragma unroll
    for (int j = 0; j < 8; ++j) {
        aiv[j] = att[head * 64 + (cx & 3) * 8 + j];
        ajv[j] = att[head * 64 + 32 + (cx & 3) * 8 + j];
    }
    #pragma unroll
    for (int i = 0; i < 4; ++i) {
        int gr = rbase + ry * 4 + i;
        float pi = 0.f, pj = 0.f;
        #pragma unroll
        for (int j = 0; j < 8; ++j) {
            pi += acc[i][j] * aiv[j];
            pj += acc[i][j] * ajv[j];
        }
        pi += __shfl_xor(pi, 1); pi += __shfl_xor(pi, 2);
        pj += __shfl_xor(pj, 1); pj += __shfl_xor(pj, 2);
        if (gr < NN) {
            float* dst = hbuf + (size_t)gr * 128 + cx * 8;
            *reinterpret_cast<float4*>(dst)     = make_float4(acc[i][0], acc[i][1], acc[i][2], acc[i][3]);
            *reinterpret_cast<float4*>(dst + 4) = make_float4(acc[i][4], acc[i][5], acc[i][6], acc[i][7]);
            if ((cx & 3) == 0) {
                s_i[(size_t)gr * 4 + head] = pi;
                s_j[(size_t)gr * 4 + head] = pj;
            }
        }
    }

    // publish bases (atomic returns have had the whole compute to land), scatter
    if (t < NB) base[t] = myBase;
    __syncthreads();
    if (ev) {
        int rows[4] = {er.x, er.y, er.z, er.w};
        int cols[4] = {ec.x, ec.y, ec.z, ec.w};
        #pragma unroll
        for (int i = 0; i < 4; ++i) {
            u32 pos = base[bk[i]] + lrk[i];
            if (pos < BCAP)
                breg[(size_t)bk[i] * BCAP + pos] = ((u32)(rows[i] & 255) << 16) | (u32)cols[i];
        }
    }
}

// ---------------- rowsel: LDS CSR build + top-k + softmax + aggregate ----------------
// 4 sub-blocks per bucket, 64 rows each. Block re-reads its bucket's packed
// edges (~16KB, L2-hot), LDS-atomics build u16 lcsr[64][66]. Top-k: 1 thread
// per (row,head); softmax thread-local. u16 lcsr/lcl -> 21 KB LDS -> 7
// blocks/CU: the whole 784-block grid is co-resident (R9: 23% occupancy was
// the latency-hiding limiter). Key = sortable-float(s_j)<<32 | ~slot; slot
// tie-break exact (distinct-col ties measure-zero, same-col output-invariant,
// self-loop ~(NE+row) last among equals).
__global__ __launch_bounds__(256) void rowsel_k(const int* __restrict__ cursor,
                                                const u32* __restrict__ breg,
                                                const float* __restrict__ s_i,
                                                const float* __restrict__ s_j,
                                                const float* __restrict__ hbuf,
                                                float* __restrict__ out) {
    __shared__ u16 lcsr[64][66];        // 8.25 KB (pad 66: banking)
    __shared__ u32 ldeg[64];
    __shared__ float lal[256 * 8];      // 8 KB
    __shared__ u16  lcl[256 * 8];       // 4 KB
    const int t = threadIdx.x;
    const int B = blockIdx.x >> 2;
    const int s = blockIdx.x & 3;
    const int rbase = B * 256 + s * 64;

    if (t < 64) ldeg[t] = 0;
    __syncthreads();

    int n = cursor[B * CURSTRIDE];
    if (n > BCAP) n = BCAP;
    const u32* reg = breg + (size_t)B * BCAP;
    for (int i = t; i < n; i += 256) {
        u32 e = reg[i];
        if ((int)(e >> 22) == s) {
            int lr = (int)((e >> 16) & 63);
            u32 rk = atomicAdd(&ldeg[lr], 1u);
            if (rk < 64) lcsr[lr][rk] = (u16)(e & 0xFFFFu);
        }
    }
    __syncthreads();

    // top-k: thread t = lrow*4 + head
    const int lrow = t >> 2;
    const int head = t & 3;
    const int row = rbase + lrow;

    u64 kl[TOPK];
    int cl[TOPK];
    #pragma unroll
    for (int i = 0; i < TOPK; ++i) { kl[i] = 0ull; cl[i] = 0; }

    int dgr = 0;
    if (row < NN) {
        dgr = (int)ldeg[lrow];
        if (dgr > 64) dgr = 64;
        // synthetic self-loop candidate (loses ties to any real slot)
        float v = s_j[(size_t)row * 4 + head];
        u32 b = __float_as_uint(v);
        u32 fk = (b & 0x80000000u) ? ~b : (b | 0x80000000u);
        kl[0] = ((u64)fk << 32) | (u32)(~(u32)(NE + row));
        cl[0] = row;
    }

    for (int j = 0; j < dgr; ++j) {
        int col = (int)lcsr[lrow][j];
        float v = s_j[(size_t)col * 4 + head];
        u32 b = __float_as_uint(v);
        u32 fk = (b & 0x80000000u) ? ~b : (b | 0x80000000u);
        u64 key = ((u64)fk << 32) | (u32)(~(u32)j);
        int cc = col;
        if (key > kl[TOPK - 1]) {
            #pragma unroll
            for (int i = 0; i < TOPK; ++i) {
                bool gt = key > kl[i];
                u64 tk = gt ? kl[i] : key;  kl[i] = gt ? key : kl[i];  key = tk;
                int tc = gt ? cl[i] : cc;   cl[i] = gt ? cc : cl[i];   cc = tc;
            }
        }
    }

    // softmax: fully thread-local (kl[0] is the max)
    {
        float si = (row < NN) ? s_i[(size_t)row * 4 + head] : 0.f;
        u32 fk = (u32)(kl[0] >> 32);
        u32 b = (fk & 0x80000000u) ? (fk ^ 0x80000000u) : ~fk;
        float vmax = __uint_as_float(b);
        float em = si + vmax;
        float m = (em >= 0.f) ? em : 0.2f * em;
        float al[TOPK];
        float denom = 0.f;
        #pragma unroll
        for (int i = 0; i < TOPK; ++i) {
            u32 fki = (u32)(kl[i] >> 32);
            u32 bi = (fki & 0x80000000u) ? (fki ^ 0x80000000u) : ~fki;
            float v = __uint_as_float(bi);
            float e = si + v;
            e = (e >= 0.f) ? e : 0.2f * e;
            float z = (kl[i] != 0ull) ? __expf(e - m) : 0.f;
            al[i] = z;
            denom += z;
        }
        float inv = 1.f / denom;
        #pragma unroll
        for (int i = 0; i < TOPK; ++i) {
            lal[t * 8 + i] = al[i] * inv;
            lcl[t * 8 + i] = (u16)cl[i];
        }
    }
    __syncthreads();

    // phase 2: 256 (row,head) pairs; lane=(pair q, float4 slot dq);
    // 8 independent 16B gathers in flight per lane, 1KB per load/store inst.
    const int lane = t & 63;
    const int wid = t >> 6;
    const int q = lane >> 3;
    const int dq = lane & 7;
    for (int g = wid; g < 32; g += 4) {
        const int p = g * 8 + q;          // pair 0..255 == lrow*4+hh
        const int r = rbase + (p >> 2);
        const int hh = p & 3;
        if (r < NN) {
            const int base = p * 8;
            float av[8]; int cv[8];
            #pragma unroll
            for (int k = 0; k < 8; ++k) { av[k] = lal[base + k]; cv[k] = (int)lcl[base + k]; }
            float4 a4 = make_float4(0.f, 0.f, 0.f, 0.f);
            #pragma unroll
            for (int k = 0; k < 8; ++k) {
                const float4 hv = *reinterpret_cast<const float4*>(
                    &hbuf[(size_t)cv[k] * 128 + hh * 32 + dq * 4]);
                a4.x += av[k] * hv.x;
                a4.y += av[k] * hv.y;
                a4.z += av[k] * hv.z;
                a4.w += av[k] * hv.w;
            }
            a4.x = (a4.x > 0.f) ? a4.x : expm1f(a4.x);
            a4.y = (a4.y > 0.f) ? a4.y : expm1f(a4.y);
            a4.z = (a4.z > 0.f) ? a4.z : expm1f(a4.z);
            a4.w = (a4.w > 0.f) ? a4.w : expm1f(a4.w);
            *reinterpret_cast<float4*>(&out[(size_t)r * 128 + hh * 32 + dq * 4]) = a4;
        }
    }
}

extern "C" void kernel_launch(void* const* d_in, const int* in_sizes, int n_in,
                              void* d_out, int out_size, void* d_ws, size_t ws_size,
                              hipStream_t stream) {
    const float* x   = (const float*)d_in[0];   // 50000x128 f32
    const float* W   = (const float*)d_in[1];   // 128x128  f32
    const float* att = (const float*)d_in[2];   // 4x64     f32
    const int*   ei  = (const int*)d_in[3];     // 2x800000 int32
    float* out = (float*)d_out;                 // 50000x128 f32

    u32* breg    = (u32*)d_ws;                  // 196*4608 u32 = 3.6 MB
    float* hbuf  = (float*)(breg + (size_t)NB * BCAP);  // 6.4M f32 = 25.6 MB
    float* s_i   = hbuf + 6400000;              // 200k f32
    float* s_j   = s_i + 200000;                // 200k f32
    int* cursor  = (int*)(s_j + 200000);        // 196*16 ints (64B-padded)
    // total ws: ~31 MB

    hipMemsetAsync(cursor, 0, NB * CURSTRIDE * sizeof(int), stream);
    gemm_k<<<GTILES, 256, 0, stream>>>(x, W, att, ei, hbuf, s_i, s_j, cursor, breg);
    rowsel_k<<<NB * 4, 256, 0, stream>>>(cursor, breg, s_i, s_j, hbuf, out);
}